// Round 5
// baseline (840.573 us; speedup 1.0000x reference)
//
#include <hip/hip_runtime.h>
#include <math.h>

// B=8, m=197, dim=512, heads=8, depth=2, F=8, tdim=1576, cdim=64, ncls=1000.
namespace {

typedef unsigned short u16;
typedef __attribute__((ext_vector_type(8))) short bf16x8;
typedef __attribute__((ext_vector_type(4))) float f32x4;

constexpr int NB = 8, NM = 197, ND = 512, NH = 8, NTD = 1576, NC = 64;
constexpr long XSZ = (long)NB * NM * ND;        // 806912
constexpr long QSZ = (long)NH * NB * NM * ND;   // 6455296 elts (h, b*m, e)
constexpr long TABSZ = 50432;                   // 197*256 == 64*788
constexpr int MP = 208;                         // padded 197 (16B-aligned bf16 rows)

__device__ __forceinline__ u16 f2bf(float f) {
  union { float f; unsigned u; } v; v.f = f;
  unsigned r = v.u + 0x7FFF + ((v.u >> 16) & 1);
  return (u16)(r >> 16);
}
__device__ __forceinline__ float bf2f(u16 h) {
  union { unsigned u; float f; } v; v.u = ((unsigned)h) << 16;
  return v.f;
}
__device__ __forceinline__ void async_cp16(const void* g, void* l) {
  __builtin_amdgcn_global_load_lds((const __attribute__((address_space(1))) unsigned*)g,
                                   (__attribute__((address_space(3))) unsigned*)l, 16, 0, 0);
}

// ---------------------------------------------------------------------------
__global__ void rope_tables_kernel(float* cosP, float* sinP, float* cosT, float* sinT) {
  int idx = blockIdx.x * 256 + threadIdx.x;
  if (idx < 197 * 256) {
    int p = idx / 256, i = idx % 256;
    float theta = powf(10000.f, -2.f * ((float)i - 1.f) / 512.f);
    float a = (float)p * theta;
    cosP[idx] = cosf(a); sinP[idx] = sinf(a);
  }
  int j = idx - 197 * 256;
  if (j >= 0 && j < 64 * 788) {
    int p = j / 788, i = j % 788;
    float theta = powf(10000.f, -2.f * ((float)i - 1.f) / 1576.f);
    float a = (float)p * theta;
    cosT[j] = cosf(a); sinT[j] = sinf(a);
  }
}

// ---------------------------------------------------------------------------
// Gather img patches into bf16 A-matrix: pimg[b*196+p][k], k=(pp*16+qq)*3+cc.
__global__ void patch_gather_kernel(const float* __restrict__ img, u16* __restrict__ pimg) {
  long idx = (long)blockIdx.x * 256 + threadIdx.x;
  if (idx >= 1568L * 768) return;
  int r = (int)(idx / 768), k = (int)(idx % 768);
  int b = r / 196, p = r - b * 196;
  int pi = p / 14, pj = p - pi * 14;
  int cc = k % 3, pq = k / 3, pp = pq >> 4, qq = pq & 15;
  pimg[idx] = f2bf(img[((long)(b * 3 + cc) * 224 + pi * 16 + pp) * 224 + pj * 16 + qq]);
}

__global__ void cls_fill_kernel(const float* __restrict__ cls, float* __restrict__ x) {
  int idx = blockIdx.x * 256 + threadIdx.x;
  if (idx >= 8 * 512) return;
  int b = idx >> 9, e = idx & 511;
  x[((long)b * NM) * ND + e] = cls[e];
}

// ---------------------------------------------------------------------------
// Two-stage per-batch RMS: part64[b*8+i] partial sums of squares.
__global__ void rms_part_kernel(const float* __restrict__ x, float* __restrict__ part64) {
  int i = blockIdx.x, b = blockIdx.y;
  const float* p = x + (long)b * NM * ND + (long)i * 12608;
  float s = 0.f;
  for (int j = threadIdx.x; j < 12608; j += 256) { float v = p[j]; s += v * v; }
  __shared__ float red[256];
  red[threadIdx.x] = s; __syncthreads();
  for (int off = 128; off; off >>= 1) {
    if (threadIdx.x < off) red[threadIdx.x] += red[threadIdx.x + off];
    __syncthreads();
  }
  if (threadIdx.x == 0) part64[b * 8 + i] = red[0];
}

__device__ __forceinline__ float rms_inv(const float* part64, int b) {
  float ssum = 0.f;
#pragma unroll
  for (int i = 0; i < 8; i++) ssum += part64[b * 8 + i];
  return sqrtf((float)(NM * ND) / ssum);
}

// Phase A: writes xn (fp32), xnb (bf16), and pre-seeds x = xn + attn_bias
// (the attn-proj GEMM then atomicAdds its per-head partial sums into x).
__global__ void rms_apply_kernel(const float* __restrict__ x_in, const float* __restrict__ scale,
                                 const float* __restrict__ part64, const float* __restrict__ bias,
                                 float* __restrict__ x, float* __restrict__ xn,
                                 u16* __restrict__ xnb) {
  long idx = (long)blockIdx.x * 256 + threadIdx.x;
  if (idx >= XSZ) return;
  int b = (int)(idx / (NM * ND));
  long md = idx % (NM * ND);
  float v = x_in[idx] * scale[md] * rms_inv(part64, b);
  xn[idx] = v;
  xnb[idx] = f2bf(v);
  x[idx] = v + bias[(int)(md % ND)];
}

// Phase-B variant: writes xn (residual) and the permuted token matrix yb.
__global__ void rms_apply_tok_kernel(const float* __restrict__ x, const float* __restrict__ scale,
                                     const float* __restrict__ part64, float* __restrict__ xn,
                                     u16* __restrict__ yb) {
  long idx = (long)blockIdx.x * 256 + threadIdx.x;
  if (idx >= XSZ) return;
  int b = (int)(idx / (NM * ND));
  long md = idx % (NM * ND);
  float v = x[idx] * scale[md] * rms_inv(part64, b);
  xn[idx] = v;
  int mm = (int)(md / ND), d = (int)(md % ND);
  int c = d >> 3, f = d & 7;
  yb[((long)b * 64 + c) * NTD + f * 197 + mm] = f2bf(v);
}

// ---------------------------------------------------------------------------
// bf16 MFMA GEMM: C(MxN) = alpha * A(MxK) * B^T(NxK). 128x128 tile, BK=32,
// 4 waves (2x2, each 64x64 = 4x4 tiles of 16x16x32). Double-buffered
// global_load_lds staging, XOR-swizzled LDS layout (2-way residual conflict).
// EPI_QKV:   z1=0/1 -> rope(cosP/sinP, stride 256, t=gr%197) -> q/k bf16;
//            z1=2 -> v transposed (h,b,e,m_pad). Layout contract: k=C+QSZ, vt=C+2*QSZ.
// EPI_TOKQKV:z1=0/1 -> rope(cosT/sinT, stride 788, t=gr&63) -> tq/tk bf16;
//            z1=2 -> tv transposed (b,1576,64). Contract: tk=C+XSZ, tvt=C+2*XSZ.
// EPI_ATOMIC: atomicAdd into fp32 C (attn-proj head partials).
enum { EPI_BF16 = 0, EPI_F32 = 1, EPI_TOKPV = 3, EPI_PATCH = 4,
       EPI_QKV = 5, EPI_TOKQKV = 6, EPI_ATOMIC = 7 };

template <int EPI>
__global__ __launch_bounds__(256) void mfma_gemm(
    const u16* __restrict__ A, const u16* __restrict__ B, void* __restrict__ Cv,
    const float* __restrict__ resid, const float* __restrict__ ctab,
    const float* __restrict__ stab,
    int M, int N, int K, int ksplit,
    int lda, int ldb, int ldc, float alpha, int nz2,
    long aS2, long bS1, long bS2, long cS1, long cS2) {
  int z = blockIdx.z;
  int z1 = z / nz2, z2 = z - z1 * nz2;
  int kbeg = 0, kend = K;
  if (ksplit > 0) { kbeg = z2 * ksplit; kend = kbeg + ksplit; if (kend > K) kend = K; }
  A += z2 * aS2 + kbeg;
  B += z1 * bS1 + z2 * bS2 + kbeg;
  const int KL = kend - kbeg;

  __shared__ __align__(16) u16 As[2 * 4096];
  __shared__ __align__(16) u16 Bs[2 * 4096];
  const int tid = threadIdx.x;
  const int lane = tid & 63, wave = tid >> 6;
  const int wm = wave >> 1, wn = wave & 1;
  const int l15 = lane & 15, quad = lane >> 4;
  const int row0 = blockIdx.y * 128, col0 = blockIdx.x * 128;

  f32x4 acc[4][4] = {};
  const int nfull = KL >> 5, tail = KL & 31;

  auto stage = [&](int ch, int bi) {
    const int k0 = ch << 5;
#pragma unroll
    for (int e = 0; e < 2; e++) {
      int idx = e * 256 + tid;
      int r = idx >> 2, slot = idx & 3;
      int c = ((slot ^ ((r >> 1) & 3)) << 3);   // XOR swizzle at the source
      int gr = row0 + r; if (gr >= M) gr = M - 1;
      int gc = col0 + r; if (gc >= N) gc = N - 1;
      int lb = bi + (e * 256 + (tid & ~63)) * 8;
      async_cp16(A + (long)gr * lda + k0 + c, &As[lb]);
      async_cp16(B + (long)gc * ldb + k0 + c, &Bs[lb]);
    }
  };
  auto compute = [&](int bi) {
    bf16x8 af[4], bg[4];
#pragma unroll
    for (int i = 0; i < 4; i++) {
      int row = wm * 64 + i * 16 + l15;
      af[i] = *(const bf16x8*)&As[bi + row * 32 + ((quad ^ ((row >> 1) & 3)) << 3)];
    }
#pragma unroll
    for (int j = 0; j < 4; j++) {
      int row = wn * 64 + j * 16 + l15;
      bg[j] = *(const bf16x8*)&Bs[bi + row * 32 + ((quad ^ ((row >> 1) & 3)) << 3)];
    }
#pragma unroll
    for (int i = 0; i < 4; i++)
#pragma unroll
      for (int j = 0; j < 4; j++)
        acc[i][j] = __builtin_amdgcn_mfma_f32_16x16x32_bf16(af[i], bg[j], acc[i][j], 0, 0, 0);
  };

  if (nfull > 0) stage(0, 0);
  for (int ch = 0; ch < nfull; ch++) {
    __syncthreads();
    if (ch + 1 < nfull) stage(ch + 1, ((ch + 1) & 1) * 4096);
    compute((ch & 1) * 4096);
  }
  if (tail) {
    const int tb = (nfull & 1) * 4096;
    const int k0 = nfull << 5;
    if (nfull > 0) __syncthreads();
    for (int idx = tid; idx < 4096; idx += 256) {
      int r = idx >> 5, c = idx & 31;
      int g = ((((c >> 3) ^ ((r >> 1) & 3)) << 3)) | (c & 7);
      int gr = row0 + r; if (gr >= M) gr = M - 1;
      int gc = col0 + r; if (gc >= N) gc = N - 1;
      As[tb + idx] = (g < tail) ? A[(long)gr * lda + k0 + g] : (u16)0;
      Bs[tb + idx] = (g < tail) ? B[(long)gc * ldb + k0 + g] : (u16)0;
    }
    __syncthreads();
    compute(tb);
  }

  float* Cf = (float*)Cv;
  u16* Ch = (u16*)Cv;
  const long cbase = z1 * cS1 + z2 * cS2;
#pragma unroll
  for (int i = 0; i < 4; i++)
#pragma unroll
    for (int j = 0; j < 4; j++)
#pragma unroll
      for (int reg = 0; reg < 4; reg++) {
        int gr = row0 + wm * 64 + i * 16 + quad * 4 + reg;
        int gc = col0 + wn * 64 + j * 16 + l15;
        float vv = acc[i][j][reg] * alpha;
        if (EPI == EPI_QKV || EPI == EPI_TOKQKV) {
          if (z1 < 2) {
            // RoPE in the epilogue: pair partner is the adjacent l15 lane.
            const int stride = (EPI == EPI_QKV) ? 256 : 788;
            const int tmod = (EPI == EPI_QKV) ? (gr % 197) : (gr & 63);
            int ii = gc >> 1;
            if (EPI == EPI_TOKQKV && ii > 787) ii = 787;
            float cv = ctab[(long)tmod * stride + ii];
            float sv = stab[(long)tmod * stride + ii];
            float pv = __shfl_xor(vv, 1);
            float ov = (gc & 1) ? (vv * cv - pv * sv) : (vv * cv + pv * sv);
            if (gr < M && gc < N) {
              if (EPI == EPI_QKV)
                Ch[(long)z1 * QSZ + (long)z2 * cS2 + (long)gr * ldc + gc] = f2bf(ov);
              else
                Ch[(long)z1 * XSZ + (long)gr * ldc + gc] = f2bf(ov);
            }
          } else if (gr < M && gc < N) {
            if (EPI == EPI_QKV) {       // v: (h, b, e, m_pad)
              int b = gr / 197, mm = gr - b * 197;
              Ch[2 * QSZ + ((long)(z2 * 8 + b) * 512 + gc) * MP + mm] = f2bf(vv);
            } else {                    // tv: (b, 1576, 64)
              Ch[2 * XSZ + ((long)(gr >> 6) * NTD + gc) * 64 + (gr & 63)] = f2bf(vv);
            }
          }
          continue;
        }
        if (gr >= M || gc >= N) continue;
        if (EPI == EPI_BF16) {
          Ch[cbase + (long)gr * ldc + gc] = f2bf(vv);
        } else if (EPI == EPI_F32) {
          Cf[cbase + (long)gr * ldc + gc] = vv;
        } else if (EPI == EPI_ATOMIC) {
          atomicAdd(&Cf[cbase + (long)gr * ldc + gc], vv);
        } else if (EPI == EPI_TOKPV) {    // x[b][mm][c*8+f] = acc + xn
          int f = gc / 197, mm = gc - f * 197;
          long o = ((long)z2 * 197 + mm) * 512 + gr * 8 + f;
          Cf[o] = vv + resid[o];
        } else {                          // PATCH: x[b][1+p][gc] = acc + bias
          int b = gr / 196, p = gr - b * 196;
          Cf[((long)b * 197 + 1 + p) * 512 + gc] = vv + resid[gc];
        }
      }
}

// ---------------------------------------------------------------------------
// Token scores, split-K: grid (split=8, b=8). tsp[(s*8+b)][64][64] partials.
__global__ __launch_bounds__(256) void token_scores_kernel(const u16* __restrict__ tq,
                                                           const u16* __restrict__ tk,
                                                           float* __restrict__ tsp) {
  int s = blockIdx.x, b = blockIdx.y;
  const u16* A = tq + (long)b * 64 * NTD;
  const u16* B = tk + (long)b * 64 * NTD;
  __shared__ __align__(16) u16 As[64 * 32];
  __shared__ __align__(16) u16 Bs[64 * 32];
  int tid = threadIdx.x, lane = tid & 63, w = tid >> 6;
  int l15 = lane & 15, quad = lane >> 4;
  f32x4 acc[4] = {};
  int ch0 = s * 6, ch1 = (s == 7) ? 49 : s * 6 + 6;
  for (int ch = ch0; ch < ch1; ch++) {
    __syncthreads();
    int r = tid >> 2, slot = tid & 3;
    int c = ((slot ^ ((r >> 1) & 3)) << 3);
    async_cp16(A + (long)r * NTD + ch * 32 + c, &As[(tid & ~63) * 8]);
    async_cp16(B + (long)r * NTD + ch * 32 + c, &Bs[(tid & ~63) * 8]);
    __syncthreads();
    int row = w * 16 + l15;
    bf16x8 av = *(const bf16x8*)&As[row * 32 + ((quad ^ ((row >> 1) & 3)) << 3)];
#pragma unroll
    for (int j = 0; j < 4; j++) {
      int rb = j * 16 + l15;
      bf16x8 bv = *(const bf16x8*)&Bs[rb * 32 + ((quad ^ ((rb >> 1) & 3)) << 3)];
      acc[j] = __builtin_amdgcn_mfma_f32_16x16x32_bf16(av, bv, acc[j], 0, 0, 0);
    }
  }
  if (s == 7) {  // 8-element K tail
    __syncthreads();
    for (int idx = tid; idx < 64 * 32; idx += 256) {
      int r = idx >> 5, c = idx & 31;
      int g = ((((c >> 3) ^ ((r >> 1) & 3)) << 3)) | (c & 7);
      As[idx] = (g < 8) ? A[(long)r * NTD + 1568 + g] : (u16)0;
      Bs[idx] = (g < 8) ? B[(long)r * NTD + 1568 + g] : (u16)0;
    }
    __syncthreads();
    int row = w * 16 + l15;
    bf16x8 av = *(const bf16x8*)&As[row * 32 + ((quad ^ ((row >> 1) & 3)) << 3)];
#pragma unroll
    for (int j = 0; j < 4; j++) {
      int rb = j * 16 + l15;
      bf16x8 bv = *(const bf16x8*)&Bs[rb * 32 + ((quad ^ ((rb >> 1) & 3)) << 3)];
      acc[j] = __builtin_amdgcn_mfma_f32_16x16x32_bf16(av, bv, acc[j], 0, 0, 0);
    }
  }
  const float sc = rsqrtf(1576.f);
  float* dst = tsp + ((long)(s * 8 + b)) * 4096;
#pragma unroll
  for (int j = 0; j < 4; j++)
#pragma unroll
    for (int reg = 0; reg < 4; reg++) {
      int row = w * 16 + quad * 4 + reg, col = j * 16 + l15;
      dst[row * 64 + col] = acc[j][reg] * sc;
    }
}

// ---------------------------------------------------------------------------
// Spatial softmax: s fp32 (64,197,197) -> pb bf16 (64,197,208). 4 rows/block.
__global__ void softmax_spatial_kernel(const float* __restrict__ s, u16* __restrict__ pb) {
  int row = blockIdx.x * 4 + (threadIdx.x >> 6);
  int lane = threadIdx.x & 63;
  const float* p = s + (long)row * 197;
  int hb = row / 197, mm = row - hb * 197;
  u16* q = pb + (long)hb * 197 * MP + (long)mm * MP;
  float mx = -INFINITY;
  for (int j = lane; j < 197; j += 64) mx = fmaxf(mx, p[j]);
#pragma unroll
  for (int off = 32; off; off >>= 1) mx = fmaxf(mx, __shfl_xor(mx, off));
  float sum = 0.f;
  float ev[4];
  int cnt = 0;
  for (int j = lane; j < 197; j += 64) { ev[cnt] = expf(p[j] - mx); sum += ev[cnt]; cnt++; }
#pragma unroll
  for (int off = 32; off; off >>= 1) sum += __shfl_xor(sum, off);
  float inv = 1.f / sum;
  cnt = 0;
  for (int j = lane; j < 197; j += 64) { q[j] = f2bf(ev[cnt] * inv); cnt++; }
}

// Token softmax: sums 8 split-K partials, softmaxes, writes Pb bf16.
__global__ void softmax_token_kernel(const float* __restrict__ tsp, u16* __restrict__ Pb) {
  int row = blockIdx.x * 4 + (threadIdx.x >> 6);  // 0..511 = b*64+r
  int lane = threadIdx.x & 63;
  int b = row >> 6, r = row & 63;
  float v = 0.f;
#pragma unroll
  for (int p = 0; p < 8; p++) v += tsp[((long)(p * 8 + b)) * 4096 + r * 64 + lane];
  float mx = v;
#pragma unroll
  for (int off = 32; off; off >>= 1) mx = fmaxf(mx, __shfl_xor(mx, off));
  float e = expf(v - mx);
  float sum = e;
#pragma unroll
  for (int off = 32; off; off >>= 1) sum += __shfl_xor(sum, off);
  Pb[(long)row * 64 + lane] = f2bf(e / sum);
}

// ---------------------------------------------------------------------------
// Transpose fp32 (RxC) -> bf16 (CxR), batched over blockIdx.z.
__global__ void transpose_bf16_kernel(const float* __restrict__ src, u16* __restrict__ dst,
                                      int R, int C, long sS, long dS) {
  src += (long)blockIdx.z * sS;
  dst += (long)blockIdx.z * dS;
  __shared__ float t[32][33];
  int c0 = blockIdx.x * 32, r0 = blockIdx.y * 32;
  int tx = threadIdx.x, ty = threadIdx.y;
#pragma unroll
  for (int i = 0; i < 4; i++) {
    int r = r0 + ty + i * 8;
    if (r < R && c0 + tx < C) t[ty + i * 8][tx] = src[(long)r * C + c0 + tx];
  }
  __syncthreads();
#pragma unroll
  for (int i = 0; i < 4; i++) {
    int c = c0 + ty + i * 8;
    if (c < C && r0 + tx < R) dst[(long)c * R + r0 + tx] = f2bf(t[tx][ty + i * 8]);
  }
}

// Merged Wq/Wk/Wv transpose: grid (16,16,48), z = w*16 + (l*8+h).
__global__ void w_transpose3_kernel(const float* __restrict__ Wq, const float* __restrict__ Wk,
                                    const float* __restrict__ Wv, u16* __restrict__ dst) {
  int z = blockIdx.z;
  int w = z >> 4, lh = z & 15;
  const float* src = (w == 0 ? Wq : w == 1 ? Wk : Wv) + (long)lh * 262144;
  u16* d = dst + (long)z * 262144;
  __shared__ float t[32][33];
  int c0 = blockIdx.x * 32, r0 = blockIdx.y * 32;
  int tx = threadIdx.x, ty = threadIdx.y;
#pragma unroll
  for (int i = 0; i < 4; i++)
    t[ty + i * 8][tx] = src[(long)(r0 + ty + i * 8) * 512 + c0 + tx];
  __syncthreads();
#pragma unroll
  for (int i = 0; i < 4; i++)
    d[(long)(c0 + ty + i * 8) * 512 + r0 + tx] = f2bf(t[tx][ty + i * 8]);
}

// Merged tWq/tWk/tWv transpose: grid (50,50,6), z = w*2 + l.
__global__ void t_transpose3_kernel(const float* __restrict__ Wq, const float* __restrict__ Wk,
                                    const float* __restrict__ Wv, u16* __restrict__ dst) {
  int z = blockIdx.z;
  int w = z >> 1, l = z & 1;
  const float* src = (w == 0 ? Wq : w == 1 ? Wk : Wv) + (long)l * NTD * NTD;
  u16* d = dst + (long)z * NTD * NTD;
  __shared__ float t[32][33];
  int c0 = blockIdx.x * 32, r0 = blockIdx.y * 32;
  int tx = threadIdx.x, ty = threadIdx.y;
#pragma unroll
  for (int i = 0; i < 4; i++) {
    int r = r0 + ty + i * 8;
    if (r < NTD && c0 + tx < NTD) t[ty + i * 8][tx] = src[(long)r * NTD + c0 + tx];
  }
  __syncthreads();
#pragma unroll
  for (int i = 0; i < 4; i++) {
    int c = c0 + ty + i * 8;
    if (c < NTD && r0 + tx < NTD) d[(long)c * NTD + r0 + tx] = f2bf(t[tx][ty + i * 8]);
  }
}

// ---------------------------------------------------------------------------
// cls LayerNorm -> xs8[b][512]
__global__ void ln_kernel(const float* __restrict__ x, const float* __restrict__ g,
                          const float* __restrict__ bb, float* __restrict__ xs8) {
  int b = blockIdx.x, t = threadIdx.x;
  __shared__ float red[512];
  float v = x[((long)b * NM) * ND + t];
  red[t] = v; __syncthreads();
  for (int off = 256; off; off >>= 1) { if (t < off) red[t] += red[t + off]; __syncthreads(); }
  float mu = red[0] / 512.f; __syncthreads();
  float d = v - mu;
  red[t] = d * d; __syncthreads();
  for (int off = 256; off; off >>= 1) { if (t < off) red[t] += red[t + off]; __syncthreads(); }
  float var = red[0] / 512.f;
  xs8[b * 512 + t] = (v - mu) * rsqrtf(var + 1e-5f) * g[t] + bb[t];
}

// head GEMM: out[b][n] = xs8[b] . W[:,n] + hb[n]. grid (4,8), 256 thr.
__global__ void head_gemm_kernel(const float* __restrict__ xs8, const float* __restrict__ W,
                                 const float* __restrict__ hb, float* __restrict__ out) {
  int b = blockIdx.y;
  int n = blockIdx.x * 250 + threadIdx.x;
  __shared__ float xs[512];
  for (int i = threadIdx.x; i < 512; i += 256) xs[i] = xs8[b * 512 + i];
  __syncthreads();
  if (threadIdx.x >= 250 || n >= 1000) return;
  float acc = hb[n];
  for (int dd = 0; dd < 512; dd++) acc += xs[dd] * W[(long)dd * 1000 + n];
  out[(long)b * 1000 + n] = acc;
}

}  // namespace

extern "C" void kernel_launch(void* const* d_in, const int* in_sizes, int n_in,
                              void* d_out, int out_size, void* d_ws, size_t ws_size,
                              hipStream_t stream) {
  const float* img     = (const float*)d_in[0];
  const float* patch_W = (const float*)d_in[1];
  const float* patch_b = (const float*)d_in[2];
  const float* cls_tok = (const float*)d_in[3];
  const float* rms_s   = (const float*)d_in[4];
  const float* Wq      = (const float*)d_in[5];
  const float* Wk      = (const float*)d_in[6];
  const float* Wv      = (const float*)d_in[7];
  const float* attn_W  = (const float*)d_in[8];
  const float* attn_b  = (const float*)d_in[9];
  const float* tWq     = (const float*)d_in[10];
  const float* tWk     = (const float*)d_in[11];
  const float* tWv     = (const float*)d_in[12];
  const float* ln_g    = (const float*)d_in[13];
  const float* ln_b    = (const float*)d_in[14];
  const float* head_W  = (const float*)d_in[15];
  const float* head_b  = (const float*)d_in[16];
  float* out = (float*)d_out;

  // ---- workspace layout (floats) ----
  float* base = (float*)d_ws;
  long off = 0;
  auto alloc = [&](long n) { float* r = base + off; off += (n + 15) & ~15L; return r; };
  float* cosP = alloc(TABSZ);
  float* sinP = alloc(TABSZ);
  float* cosT = alloc(TABSZ);
  float* sinT = alloc(TABSZ);
  float* x    = alloc(XSZ);
  float* xn   = alloc(XSZ);
  float* Wt_f   = alloc(6291456);   // (w,l,h) 512x512 bf16, 48 slabs
  float* Wat_f  = alloc(2097152);   // (l) 512x4096 bf16
  float* tWt_f  = alloc(7451328);   // (w,l) 1576x1576 bf16
  float* xnb_f  = alloc(XSZ / 2);
  float* pimg_f = alloc(602112);    // 1568x768 bf16
  float* pWt_f  = alloc(196608);    // 512x768 bf16
  float* xs8    = alloc(4096);
  float* U      = alloc(16885824);  // union region
  float* ff     = alloc(64);

  u16* Wt16  = (u16*)Wt_f;
  u16* Wat16 = (u16*)Wat_f;
  u16* tWt16 = (u16*)tWt_f;
  u16* xnb   = (u16*)xnb_f;
  u16* pimg  = (u16*)pimg_f;
  u16* pWt   = (u16*)pWt_f;
  // phase A overlay (contract: kk = q + QSZ, vt = q + 2*QSZ)
  u16* q   = (u16*)U;                 // 6455296 elts (h, b*m, e)
  u16* kk  = q + QSZ;                 // 6455296
  u16* vt  = kk + QSZ;                // 8*8*512*208 = 6815744 (h,b,e,m_pad)
  float* s = (float*)(vt + 6815744);  // 2483776 f  (hb,197,197)
  u16* pb  = (u16*)(s + 2483776);     // 64*197*208 = 2622464 (hb,197,208)
  u16* o   = pb + 2622464;            // 6455296 (h, b*m, e)
  // phase B overlay (contract: tkb = tqb + XSZ, tvt = tqb + 2*XSZ)
  u16* yb     = (u16*)U;              // 806912 (b*64+c, 1576)
  u16* tqb    = yb + XSZ;
  u16* tkb    = tqb + XSZ;
  u16* tvt    = tkb + XSZ;            // (b, 1576, 64)
  float* tsp  = (float*)(tvt + XSZ);  // 8 splits x 8 b x 64 x 64
  u16* Pb     = (u16*)(tsp + 262144); // 8*64*64

  const float rs512 = 1.f / sqrtf(512.f);
  const dim3 tt(32, 8);

  rope_tables_kernel<<<(2 * (int)TABSZ + 255) / 256, 256, 0, stream>>>(cosP, sinP, cosT, sinT);

  // ---- patch embed via MFMA ----
  patch_gather_kernel<<<4704, 256, 0, stream>>>(img, pimg);
  transpose_bf16_kernel<<<dim3(16, 24, 1), tt, 0, stream>>>(patch_W, pWt, 768, 512, 0, 0);
  cls_fill_kernel<<<16, 256, 0, stream>>>(cls_tok, x);
  mfma_gemm<EPI_PATCH><<<dim3(4, 13, 1), 256, 0, stream>>>(
      pimg, pWt, x, patch_b, nullptr, nullptr,
      1568, 512, 768, 0, 768, 768, 512, 1.f, 1, 0, 0, 0, 0, 0);

  // ---- weight transpose + bf16 convert (4 launches) ----
  w_transpose3_kernel<<<dim3(16, 16, 48), tt, 0, stream>>>(Wq, Wk, Wv, Wt16);
  transpose_bf16_kernel<<<dim3(16, 128, 2), tt, 0, stream>>>(
      attn_W, Wat16, 4096, 512, (long)4096 * 512, (long)4096 * 512);
  t_transpose3_kernel<<<dim3(50, 50, 6), tt, 0, stream>>>(tWq, tWk, tWv, tWt16);

  for (int l = 0; l < 2; l++) {
    const float* scale = rms_s + (long)l * NM * ND;
    // ---- spatial attention ----
    rms_part_kernel<<<dim3(8, 8), 256, 0, stream>>>(x, ff);
    rms_apply_kernel<<<3152, 256, 0, stream>>>(x, scale, ff, attn_b + (long)l * ND, x, xn, xnb);

    // q/k/v in one launch: z1 = weight (q rope, k rope, v transposed), z2 = head
    mfma_gemm<EPI_QKV><<<dim3(4, 13, 24), 256, 0, stream>>>(
        xnb, Wt16 + (long)l * 8 * 262144, q, nullptr, cosP, sinP,
        1576, 512, 512, 0, 512, 512, 512, 1.f, 8,
        0, 16L * 262144, 262144, QSZ, 1576L * 512);

    // scores (fp32, scaled)
    mfma_gemm<EPI_F32><<<dim3(2, 2, 64), 256, 0, stream>>>(
        q, kk, s, nullptr, nullptr, nullptr,
        197, 197, 512, 0, 512, 512, 197, rs512, 64,
        197L * 512, 0, 197L * 512, 0, 197L * 197);
    softmax_spatial_kernel<<<3152, 256, 0, stream>>>(s, pb);
    // o = P @ v
    mfma_gemm<EPI_BF16><<<dim3(4, 2, 64), 256, 0, stream>>>(
        pb, vt, o, nullptr, nullptr, nullptr,
        197, 512, 197, 0, MP, MP, 512, 1.f, 64,
        197L * MP, 0, 512L * MP, 0, 197L * 512);
    // attn-proj: per-head partial sums atomically added into pre-seeded x
    mfma_gemm<EPI_ATOMIC><<<dim3(4, 13, 8), 256, 0, stream>>>(
        o, Wat16 + (long)l * 2097152, x, nullptr, nullptr, nullptr,
        1576, 512, 512, 0, 512, 4096, 512, 1.f, 8,
        XSZ, 0, 512, 0, 0);

    // ---- token mixing ----
    rms_part_kernel<<<dim3(8, 8), 256, 0, stream>>>(x, ff);
    rms_apply_tok_kernel<<<3152, 256, 0, stream>>>(x, scale, ff, xn, yb);

    // token q/k/v in one launch: z1 = weight (tq rope, tk rope, tv transposed)
    mfma_gemm<EPI_TOKQKV><<<dim3(13, 4, 3), 256, 0, stream>>>(
        yb, tWt16 + (long)l * 2483776, tqb, nullptr, cosT, sinT,
        512, 1576, 1576, 0, 1576, 1576, 1576, 1.f, 1,
        0, 2L * 2483776, 0, 0, 0);

    token_scores_kernel<<<dim3(8, 8), 256, 0, stream>>>(tqb, tkb, tsp);
    softmax_token_kernel<<<128, 256, 0, stream>>>(tsp, Pb);
    // token PV: scatter + residual into fp32 x
    mfma_gemm<EPI_TOKPV><<<dim3(13, 1, 8), 256, 0, stream>>>(
        Pb, tvt, x, xn, nullptr, nullptr,
        64, 1576, 64, 0, 64, 64, 0, 1.f, 8,
        4096, 0, 1576L * 64, 0, 0);
  }

  ln_kernel<<<8, 512, 0, stream>>>(x, ln_g, ln_b, xs8);
  head_gemm_kernel<<<dim3(4, 8), 256, 0, stream>>>(xs8, head_W, head_b, out);
}

// Round 7
// 778.820 us; speedup vs baseline: 1.0793x; 1.0793x over previous
//
#include <hip/hip_runtime.h>
#include <math.h>

// B=8, m=197, dim=512, heads=8, depth=2, F=8, tdim=1576, cdim=64, ncls=1000.
namespace {

typedef unsigned short u16;
typedef __attribute__((ext_vector_type(8))) short bf16x8;
typedef __attribute__((ext_vector_type(4))) float f32x4;

constexpr int NB = 8, NM = 197, ND = 512, NH = 8, NTD = 1576, NC = 64;
constexpr long XSZ = (long)NB * NM * ND;        // 806912
constexpr long QSZ = (long)NH * XSZ;            // 6455296 (h, b*m, e)
constexpr long TABSZ = 50432;                   // 197*256 == 64*788
constexpr int MP = 208;                         // padded 197 (16B-aligned bf16 rows)

__device__ __forceinline__ u16 f2bf(float f) {
  union { float f; unsigned u; } v; v.f = f;
  unsigned r = v.u + 0x7FFF + ((v.u >> 16) & 1);
  return (u16)(r >> 16);
}
__device__ __forceinline__ void async_cp16(const void* g, void* l) {
  __builtin_amdgcn_global_load_lds((const __attribute__((address_space(1))) unsigned*)g,
                                   (__attribute__((address_space(3))) unsigned*)l, 16, 0, 0);
}

// ---------------------------------------------------------------------------
// Shared MFMA GEMM core: acc += A(M x KL) * B^T(N x KL), 128x128 tile, BK=32,
// double-buffered global_load_lds, XOR-swizzled LDS (2-way residual conflict).
__device__ __forceinline__ void gemm_core(
    const u16* __restrict__ A, int lda, int M, int row0,
    const u16* __restrict__ B, int ldb, int N, int col0,
    int KL, u16* As, u16* Bs, f32x4 (&acc)[4][4],
    int tid, int wm, int wn, int l15, int quad) {
  const int nfull = KL >> 5, tail = KL & 31;
  const int r = tid >> 2;
  const int cs = (((tid & 3) ^ ((r >> 1) & 3)) << 3);
  int gr0 = row0 + r;      if (gr0 >= M) gr0 = M - 1;
  int gr1 = row0 + r + 64; if (gr1 >= M) gr1 = M - 1;
  int gc0 = col0 + r;      if (gc0 >= N) gc0 = N - 1;
  int gc1 = col0 + r + 64; if (gc1 >= N) gc1 = N - 1;
  const u16* pa0 = A + (long)gr0 * lda + cs;
  const u16* pa1 = A + (long)gr1 * lda + cs;
  const u16* pb0 = B + (long)gc0 * ldb + cs;
  const u16* pb1 = B + (long)gc1 * ldb + cs;
  const int lb0 = (tid & ~63) * 8;
  const int lb1 = lb0 + 2048;

  auto stage = [&](int k0, int bi) {
    async_cp16(pa0 + k0, &As[bi + lb0]);
    async_cp16(pa1 + k0, &As[bi + lb1]);
    async_cp16(pb0 + k0, &Bs[bi + lb0]);
    async_cp16(pb1 + k0, &Bs[bi + lb1]);
  };
  auto compute = [&](int bi) {
    bf16x8 af[4], bg[4];
#pragma unroll
    for (int i = 0; i < 4; i++) {
      int row = wm * 64 + i * 16 + l15;
      af[i] = *(const bf16x8*)&As[bi + row * 32 + ((quad ^ ((row >> 1) & 3)) << 3)];
    }
#pragma unroll
    for (int j = 0; j < 4; j++) {
      int row = wn * 64 + j * 16 + l15;
      bg[j] = *(const bf16x8*)&Bs[bi + row * 32 + ((quad ^ ((row >> 1) & 3)) << 3)];
    }
#pragma unroll
    for (int i = 0; i < 4; i++)
#pragma unroll
      for (int j = 0; j < 4; j++)
        acc[i][j] = __builtin_amdgcn_mfma_f32_16x16x32_bf16(af[i], bg[j], acc[i][j], 0, 0, 0);
  };

  if (nfull > 0) stage(0, 0);
  for (int ch = 0; ch < nfull; ch++) {
    __syncthreads();
    if (ch + 1 < nfull) stage((ch + 1) << 5, ((ch + 1) & 1) * 4096);
    compute((ch & 1) * 4096);
  }
  if (tail) {
    const int tb = (nfull & 1) * 4096;
    const int k0f = nfull << 5;
    if (nfull > 0) __syncthreads();
    for (int idx2 = tid; idx2 < 4096; idx2 += 256) {
      int rr = idx2 >> 5, cc = idx2 & 31;
      int g = ((((cc >> 3) ^ ((rr >> 1) & 3)) << 3)) | (cc & 7);
      int grr = row0 + rr; if (grr >= M) grr = M - 1;
      int gcc = col0 + rr; if (gcc >= N) gcc = N - 1;
      As[tb + idx2] = (g < tail) ? A[(long)grr * lda + k0f + g] : (u16)0;
      Bs[tb + idx2] = (g < tail) ? B[(long)gcc * ldb + k0f + g] : (u16)0;
    }
    __syncthreads();
    compute(tb);
  }
}

// ---------------------------------------------------------------------------
// init: RoPE tables + patch gather + cls fill, one launch. grid 5114 x 256.
__global__ void init_kernel(const float* __restrict__ img, const float* __restrict__ cls,
                            float* cosP, float* sinP, float* cosT, float* sinT,
                            u16* __restrict__ pimg, float* __restrict__ x) {
  long idx = (long)blockIdx.x * 256 + threadIdx.x;
  if (idx < 197 * 256) {
    int p = (int)(idx / 256), i = (int)(idx % 256);
    float theta = powf(10000.f, -2.f * ((float)i - 1.f) / 512.f);
    float a = (float)p * theta;
    cosP[idx] = cosf(a); sinP[idx] = sinf(a);
    return;
  }
  long j = idx - 197 * 256;
  if (j < 64 * 788) {
    int p = (int)(j / 788), i = (int)(j % 788);
    float theta = powf(10000.f, -2.f * ((float)i - 1.f) / 1576.f);
    float a = (float)p * theta;
    cosT[j] = cosf(a); sinT[j] = sinf(a);
    return;
  }
  long k2 = j - 64 * 788;
  if (k2 < 1568L * 768) {
    int r = (int)(k2 / 768), k = (int)(k2 % 768);
    int b = r / 196, p = r - b * 196;
    int pi = p / 14, pj = p - pi * 14;
    int cc = k % 3, pq = k / 3, pp = pq >> 4, qq = pq & 15;
    pimg[k2] = f2bf(img[((long)(b * 3 + cc) * 224 + pi * 16 + pp) * 224 + pj * 16 + qq]);
    return;
  }
  long c2 = k2 - 1568L * 768;
  if (c2 < 8 * 512) {
    int b = (int)(c2 >> 9), e = (int)(c2 & 511);
    x[((long)b * NM) * ND + e] = cls[e];
  }
}

// ---------------------------------------------------------------------------
// Two-stage per-batch RMS.
__global__ void rms_part_kernel(const float* __restrict__ x, float* __restrict__ part64) {
  int i = blockIdx.x, b = blockIdx.y;
  const float* p = x + (long)b * NM * ND + (long)i * 12608;
  float s = 0.f;
  for (int j = threadIdx.x; j < 12608; j += 256) { float v = p[j]; s += v * v; }
  __shared__ float red[256];
  red[threadIdx.x] = s; __syncthreads();
  for (int off = 128; off; off >>= 1) {
    if (threadIdx.x < off) red[threadIdx.x] += red[threadIdx.x + off];
    __syncthreads();
  }
  if (threadIdx.x == 0) part64[b * 8 + i] = red[0];
}

__device__ __forceinline__ float rms_inv(const float* part64, int b) {
  float ssum = 0.f;
#pragma unroll
  for (int i = 0; i < 8; i++) ssum += part64[b * 8 + i];
  return sqrtf((float)(NM * ND) / ssum);
}

__global__ void rms_apply_kernel(const float* __restrict__ x, const float* __restrict__ scale,
                                 const float* __restrict__ part64, float* __restrict__ xn,
                                 u16* __restrict__ xnb) {
  long idx = (long)blockIdx.x * 256 + threadIdx.x;
  if (idx >= XSZ) return;
  int b = (int)(idx / (NM * ND));
  long md = idx % (NM * ND);
  float v = x[idx] * scale[md] * rms_inv(part64, b);
  xn[idx] = v;
  xnb[idx] = f2bf(v);
}

// Phase-B: writes xn and the permuted token matrix yb[(b*64+c)*1576 + f*197+mm].
__global__ void rms_apply_tok_kernel(const float* __restrict__ x, const float* __restrict__ scale,
                                     const float* __restrict__ part64, float* __restrict__ xn,
                                     u16* __restrict__ yb) {
  long idx = (long)blockIdx.x * 256 + threadIdx.x;
  if (idx >= XSZ) return;
  int b = (int)(idx / (NM * ND));
  long md = idx % (NM * ND);
  float v = x[idx] * scale[md] * rms_inv(part64, b);
  xn[idx] = v;
  int mm = (int)(md / ND), d = (int)(md % ND);
  int c = d >> 3, f = d & 7;
  yb[((long)b * 64 + c) * NTD + f * 197 + mm] = f2bf(v);
}

// ---------------------------------------------------------------------------
// Spatial QKV, one launch. grid (4,13,24), z = w*8+h.
// w<2: q/k = xnb(1576x512) @ Wslab^T -> (h,b*m,e) straight bf16 store.
// w=2: v^T = Wv^T(512x512) @ xnb^T -> vt (h,b,e,m_pad), lane-contiguous in m.
__global__ __launch_bounds__(256) void qkv_kernel(const u16* __restrict__ xnb,
                                                  const u16* __restrict__ WtL,
                                                  u16* __restrict__ q) {
  int z = blockIdx.z, w = z >> 3, h = z & 7;
  __shared__ __align__(16) u16 As[2 * 4096];
  __shared__ __align__(16) u16 Bs[2 * 4096];
  const int tid = threadIdx.x;
  const int lane = tid & 63, wave = tid >> 6;
  const int wm = wave >> 1, wn = wave & 1;
  const int l15 = lane & 15, quad = lane >> 4;
  f32x4 acc[4][4] = {};

  if (w < 2) {
    int row0 = blockIdx.y * 128, col0 = blockIdx.x * 128;
    const u16* B = WtL + ((long)(w * 8 + h)) * 262144;
    gemm_core(xnb, 512, 1576, row0, B, 512, 512, col0, 512, As, Bs, acc,
              tid, wm, wn, l15, quad);
    long base = (long)w * QSZ + (long)h * XSZ;
#pragma unroll
    for (int i = 0; i < 4; i++)
#pragma unroll
      for (int j = 0; j < 4; j++)
#pragma unroll
        for (int reg = 0; reg < 4; reg++) {
          int gr = row0 + wm * 64 + i * 16 + quad * 4 + reg;
          int gc = col0 + wn * 64 + j * 16 + l15;
          if (gr < 1576 && gc < 512)
            q[base + (long)gr * 512 + gc] = f2bf(acc[i][j][reg]);
        }
  } else {
    int row0 = blockIdx.x * 128, col0 = blockIdx.y * 128;
    const u16* A = WtL + ((long)(16 + h)) * 262144;
    gemm_core(A, 512, 512, row0, xnb, 512, 1576, col0, 512, As, Bs, acc,
              tid, wm, wn, l15, quad);
#pragma unroll
    for (int i = 0; i < 4; i++)
#pragma unroll
      for (int j = 0; j < 4; j++)
#pragma unroll
        for (int reg = 0; reg < 4; reg++) {
          int gr = row0 + wm * 64 + i * 16 + quad * 4 + reg;  // e
          int gc = col0 + wn * 64 + j * 16 + l15;             // b*197+mm
          if (gr < 512 && gc < 1576) {
            int b = gc / 197, mm = gc - b * 197;
            q[2 * QSZ + ((long)(h * 8 + b) * 512 + gr) * MP + mm] = f2bf(acc[i][j][reg]);
          }
        }
  }
}

// ---------------------------------------------------------------------------
// Token QKV, one launch. grid (4,13,6).
// z<4: tq/tk split-K partials (w=z>>1, seg=z&1): C = yb(512x1576) @ tW^T -> tprt[z].
// z>=4: tv^T split-K: C = tWv^T(1576x1576) @ yb^T -> tprt[4+seg] (1576x512).
__global__ __launch_bounds__(256) void tok_qkv_kernel(const u16* __restrict__ yb,
                                                      const u16* __restrict__ tWt, int l,
                                                      float* __restrict__ tprt) {
  int z = blockIdx.z;
  __shared__ __align__(16) u16 As[2 * 4096];
  __shared__ __align__(16) u16 Bs[2 * 4096];
  const int tid = threadIdx.x;
  const int lane = tid & 63, wave = tid >> 6;
  const int wm = wave >> 1, wn = wave & 1;
  const int l15 = lane & 15, quad = lane >> 4;
  f32x4 acc[4][4] = {};

  if (z < 4) {
    int w = z >> 1, seg = z & 1;
    int kbeg = seg * 800, KL = seg ? 776 : 800;
    int row0 = blockIdx.x * 128, col0 = blockIdx.y * 128;
    const u16* A = yb + kbeg;
    const u16* B = tWt + ((long)(w * 2 + l)) * 2483776 + kbeg;
    gemm_core(A, 1576, 512, row0, B, 1576, 1576, col0, KL, As, Bs, acc,
              tid, wm, wn, l15, quad);
    float* dst = tprt + (long)z * XSZ;
#pragma unroll
    for (int i = 0; i < 4; i++)
#pragma unroll
      for (int j = 0; j < 4; j++)
#pragma unroll
        for (int reg = 0; reg < 4; reg++) {
          int gr = row0 + wm * 64 + i * 16 + quad * 4 + reg;
          int gc = col0 + wn * 64 + j * 16 + l15;
          if (gr < 512 && gc < 1576) dst[(long)gr * 1576 + gc] = acc[i][j][reg];
        }
  } else {
    int seg = z - 4;
    int kbeg = seg * 800, KL = seg ? 776 : 800;
    int row0 = blockIdx.y * 128, col0 = blockIdx.x * 128;
    const u16* A = tWt + ((long)(4 + l)) * 2483776 + kbeg;
    const u16* B = yb + kbeg;
    gemm_core(A, 1576, 1576, row0, B, 1576, 512, col0, KL, As, Bs, acc,
              tid, wm, wn, l15, quad);
    float* dst = tprt + (long)(4 + seg) * XSZ;
#pragma unroll
    for (int i = 0; i < 4; i++)
#pragma unroll
      for (int j = 0; j < 4; j++)
#pragma unroll
        for (int reg = 0; reg < 4; reg++) {
          int gr = row0 + wm * 64 + i * 16 + quad * 4 + reg;
          int gc = col0 + wn * 64 + j * 16 + l15;
          if (gr < 1576 && gc < 512) dst[(long)gr * 512 + gc] = acc[i][j][reg];
        }
  }
}

// Reduce token split-K partials: rope(tq), rope(tk), transpose(tv) -> bf16.
// tqb layout contract: tkb = tqb + XSZ, tvt = tqb + 2*XSZ.
__global__ void token_finish_kernel(const float* __restrict__ tp,
                                    const float* __restrict__ cosT,
                                    const float* __restrict__ sinT,
                                    u16* __restrict__ tqb) {
  long idx = (long)blockIdx.x * 256 + threadIdx.x;
  if (idx >= XSZ) return;
  int r = (int)(idx / NTD), g = (int)(idx - (long)r * NTD);
  int t = r & 63, ii = g >> 1;
  float cv = cosT[(long)t * 788 + ii];
  float sv = sinT[(long)t * 788 + ii];
  long re = (long)r * NTD + (g & ~1), ro = re + 1;
  float ve = tp[re] + tp[XSZ + re], vo = tp[ro] + tp[XSZ + ro];
  tqb[idx] = f2bf((g & 1) ? (-ve * sv + vo * cv) : (ve * cv + vo * sv));
  ve = tp[2 * XSZ + re] + tp[3 * XSZ + re];
  vo = tp[2 * XSZ + ro] + tp[3 * XSZ + ro];
  tqb[XSZ + idx] = f2bf((g & 1) ? (-ve * sv + vo * cv) : (ve * cv + vo * sv));
  // tv: idx = g2*512 + r2 in the (1576 x 512) partial layout
  int g2 = (int)(idx >> 9), r2 = (int)(idx & 511);
  float v = tp[4 * XSZ + idx] + tp[5 * XSZ + idx];
  tqb[2 * XSZ + ((long)(r2 >> 6) * NTD + g2) * 64 + (r2 & 63)] = f2bf(v);
}

// ---------------------------------------------------------------------------
// Generic MFMA GEMM for the remaining shapes.
enum { EPI_BF16 = 0, EPI_F32 = 1, EPI_TOKPV = 3, EPI_PATCH = 4 };

template <int EPI>
__global__ __launch_bounds__(256) void mfma_gemm(
    const u16* __restrict__ A, const u16* __restrict__ B, void* __restrict__ Cv,
    const float* __restrict__ resid,
    int M, int N, int K, int lda, int ldb, int ldc, float alpha, int nz2,
    long aS2, long bS1, long bS2, long cS1, long cS2) {
  int z = blockIdx.z;
  int z1 = z / nz2, z2 = z - z1 * nz2;
  A += z2 * aS2;
  B += z1 * bS1 + z2 * bS2;
  __shared__ __align__(16) u16 As[2 * 4096];
  __shared__ __align__(16) u16 Bs[2 * 4096];
  const int tid = threadIdx.x;
  const int lane = tid & 63, wave = tid >> 6;
  const int wm = wave >> 1, wn = wave & 1;
  const int l15 = lane & 15, quad = lane >> 4;
  const int row0 = blockIdx.y * 128, col0 = blockIdx.x * 128;
  f32x4 acc[4][4] = {};
  gemm_core(A, lda, M, row0, B, ldb, N, col0, K, As, Bs, acc, tid, wm, wn, l15, quad);

  float* Cf = (float*)Cv;
  u16* Ch = (u16*)Cv;
  const long cbase = z1 * cS1 + z2 * cS2;
#pragma unroll
  for (int i = 0; i < 4; i++)
#pragma unroll
    for (int j = 0; j < 4; j++)
#pragma unroll
      for (int reg = 0; reg < 4; reg++) {
        int gr = row0 + wm * 64 + i * 16 + quad * 4 + reg;
        int gc = col0 + wn * 64 + j * 16 + l15;
        if (gr >= M || gc >= N) continue;
        float vv = acc[i][j][reg] * alpha;
        if (EPI == EPI_BF16) {
          Ch[cbase + (long)gr * ldc + gc] = f2bf(vv);
        } else if (EPI == EPI_F32) {
          Cf[cbase + (long)gr * ldc + gc] = vv;
        } else if (EPI == EPI_TOKPV) {    // x[b][mm][c*8+f] = acc + xn
          int f = gc / 197, mm = gc - f * 197;
          long o = ((long)z2 * 197 + mm) * 512 + gr * 8 + f;
          Cf[o] = vv + resid[o];
        } else {                          // PATCH: x[b][1+p][gc] = acc + bias
          int b = gr / 196, p = gr - b * 196;
          Cf[((long)b * 197 + 1 + p) * 512 + gc] = vv + resid[gc];
        }
      }
}

// ---------------------------------------------------------------------------
// Token scores, split-K: grid (split=8, b=8). tsp[(s*8+b)][64][64] partials.
__global__ __launch_bounds__(256) void token_scores_kernel(const u16* __restrict__ tq,
                                                           const u16* __restrict__ tk,
                                                           float* __restrict__ tsp) {
  int s = blockIdx.x, b = blockIdx.y;
  const u16* A = tq + (long)b * 64 * NTD;
  const u16* B = tk + (long)b * 64 * NTD;
  __shared__ __align__(16) u16 As[64 * 32];
  __shared__ __align__(16) u16 Bs[64 * 32];
  int tid = threadIdx.x, lane = tid & 63, w = tid >> 6;
  int l15 = lane & 15, quad = lane >> 4;
  f32x4 acc[4] = {};
  int ch0 = s * 6, ch1 = (s == 7) ? 49 : s * 6 + 6;
  for (int ch = ch0; ch < ch1; ch++) {
    __syncthreads();
    int r = tid >> 2, slot = tid & 3;
    int c = ((slot ^ ((r >> 1) & 3)) << 3);
    async_cp16(A + (long)r * NTD + ch * 32 + c, &As[(tid & ~63) * 8]);
    async_cp16(B + (long)r * NTD + ch * 32 + c, &Bs[(tid & ~63) * 8]);
    __syncthreads();
    int row = w * 16 + l15;
    bf16x8 av = *(const bf16x8*)&As[row * 32 + ((quad ^ ((row >> 1) & 3)) << 3)];
#pragma unroll
    for (int j = 0; j < 4; j++) {
      int rb = j * 16 + l15;
      bf16x8 bv = *(const bf16x8*)&Bs[rb * 32 + ((quad ^ ((rb >> 1) & 3)) << 3)];
      acc[j] = __builtin_amdgcn_mfma_f32_16x16x32_bf16(av, bv, acc[j], 0, 0, 0);
    }
  }
  if (s == 7) {  // 8-element K tail
    __syncthreads();
    for (int idx = tid; idx < 64 * 32; idx += 256) {
      int r = idx >> 5, c = idx & 31;
      int g = ((((c >> 3) ^ ((r >> 1) & 3)) << 3)) | (c & 7);
      As[idx] = (g < 8) ? A[(long)r * NTD + 1568 + g] : (u16)0;
      Bs[idx] = (g < 8) ? B[(long)r * NTD + 1568 + g] : (u16)0;
    }
    __syncthreads();
    int row = w * 16 + l15;
    bf16x8 av = *(const bf16x8*)&As[row * 32 + ((quad ^ ((row >> 1) & 3)) << 3)];
#pragma unroll
    for (int j = 0; j < 4; j++) {
      int rb = j * 16 + l15;
      bf16x8 bv = *(const bf16x8*)&Bs[rb * 32 + ((quad ^ ((rb >> 1) & 3)) << 3)];
      acc[j] = __builtin_amdgcn_mfma_f32_16x16x32_bf16(av, bv, acc[j], 0, 0, 0);
    }
  }
  const float sc = rsqrtf(1576.f);
  float* dst = tsp + ((long)(s * 8 + b)) * 4096;
#pragma unroll
  for (int j = 0; j < 4; j++)
#pragma unroll
    for (int reg = 0; reg < 4; reg++) {
      int row = w * 16 + quad * 4 + reg, col = j * 16 + l15;
      dst[row * 64 + col] = acc[j][reg] * sc;
    }
}

// ---------------------------------------------------------------------------
// Spatial softmax: s fp32 (64,197,197) -> pb bf16 (64,197,208). 4 rows/block.
__global__ void softmax_spatial_kernel(const float* __restrict__ s, u16* __restrict__ pb) {
  int row = blockIdx.x * 4 + (threadIdx.x >> 6);
  int lane = threadIdx.x & 63;
  const float* p = s + (long)row * 197;
  int hb = row / 197, mm = row - hb * 197;
  u16* q = pb + (long)hb * 197 * MP + (long)mm * MP;
  float mx = -INFINITY;
  for (int j = lane; j < 197; j += 64) mx = fmaxf(mx, p[j]);
#pragma unroll
  for (int off = 32; off; off >>= 1) mx = fmaxf(mx, __shfl_xor(mx, off));
  float sum = 0.f;
  float ev[4];
  int cnt = 0;
  for (int j = lane; j < 197; j += 64) { ev[cnt] = expf(p[j] - mx); sum += ev[cnt]; cnt++; }
#pragma unroll
  for (int off = 32; off; off >>= 1) sum += __shfl_xor(sum, off);
  float inv = 1.f / sum;
  cnt = 0;
  for (int j = lane; j < 197; j += 64) { q[j] = f2bf(ev[cnt] * inv); cnt++; }
}

// Token softmax: sums 8 split-K partials, softmaxes, writes Pb bf16.
__global__ void softmax_token_kernel(const float* __restrict__ tsp, u16* __restrict__ Pb) {
  int row = blockIdx.x * 4 + (threadIdx.x >> 6);  // 0..511 = b*64+r
  int lane = threadIdx.x & 63;
  int b = row >> 6, r = row & 63;
  float v = 0.f;
#pragma unroll
  for (int p = 0; p < 8; p++) v += tsp[((long)(p * 8 + b)) * 4096 + r * 64 + lane];
  float mx = v;
#pragma unroll
  for (int off = 32; off; off >>= 1) mx = fmaxf(mx, __shfl_xor(mx, off));
  float e = expf(v - mx);
  float sum = e;
#pragma unroll
  for (int off = 32; off; off >>= 1) sum += __shfl_xor(sum, off);
  Pb[(long)row * 64 + lane] = f2bf(e / sum);
}

// ---------------------------------------------------------------------------
// In-place RoPE on bf16 rows (spatial q & k, contiguous).
__global__ void rope_bf16_kernel(u16* __restrict__ x, const float* __restrict__ cosT,
                                 const float* __restrict__ sinT, long R, int D, int TM) {
  long idx = (long)blockIdx.x * 256 + threadIdx.x;
  int half = D >> 1;
  if (idx >= R * half) return;
  long r = idx / half;
  int i = (int)(idx - r * half);
  int t = (int)(r % TM);
  union { unsigned u; float f; } ue, uo;
  ue.u = ((unsigned)x[r * D + 2 * i]) << 16;
  uo.u = ((unsigned)x[r * D + 2 * i + 1]) << 16;
  float c = cosT[(long)t * half + i];
  float s = sinT[(long)t * half + i];
  x[r * D + 2 * i]     = f2bf(ue.f * c + uo.f * s);
  x[r * D + 2 * i + 1] = f2bf(-ue.f * s + uo.f * c);
}

// ---------------------------------------------------------------------------
__global__ void attn_reduce_kernel(const float* __restrict__ part, const float* __restrict__ bias,
                                   const float* __restrict__ resid, float* __restrict__ x) {
  long idx = (long)blockIdx.x * 256 + threadIdx.x;
  if (idx >= XSZ) return;
  int col = (int)(idx % ND);
  float s = resid[idx] + bias[col];
#pragma unroll
  for (int h = 0; h < 8; h++) s += part[(long)h * XSZ + idx];
  x[idx] = s;
}

// ---------------------------------------------------------------------------
// Merged Wqkv (48 slabs, z = l*24 + w*8 + h) + attn_W (16 slabs: l*8 + i).
// grid (16,16,64).
__global__ void transpose_wa_kernel(const float* __restrict__ Wq, const float* __restrict__ Wk,
                                    const float* __restrict__ Wv, const float* __restrict__ attn_W,
                                    u16* __restrict__ Wt16, u16* __restrict__ Wat16) {
  int z = blockIdx.z;
  const float* src;
  u16* dst;
  long dld;
  if (z < 48) {
    int l = z / 24, rem = z - l * 24, w = rem >> 3, h = rem & 7;
    src = (w == 0 ? Wq : w == 1 ? Wk : Wv) + (long)(l * 8 + h) * 262144;
    dst = Wt16 + (long)z * 262144;
    dld = 512;
  } else {
    int za = z - 48, l = za >> 3, i = za & 7;   // FIX: 8 row-blocks per layer
    src = attn_W + (long)l * 4096 * 512 + (long)i * 512 * 512;
    dst = Wat16 + (long)l * 512 * 4096 + (long)i * 512;
    dld = 4096;
  }
  __shared__ float t[32][33];
  int c0 = blockIdx.x * 32, r0 = blockIdx.y * 32;
  int tx = threadIdx.x, ty = threadIdx.y;
#pragma unroll
  for (int i = 0; i < 4; i++)
    t[ty + i * 8][tx] = src[(long)(r0 + ty + i * 8) * 512 + c0 + tx];
  __syncthreads();
#pragma unroll
  for (int i = 0; i < 4; i++)
    dst[(long)(c0 + ty + i * 8) * dld + r0 + tx] = f2bf(t[tx][ty + i * 8]);
}

// Generic transpose fp32 (RxC) -> bf16 (CxR) (used for patch_W).
__global__ void transpose_bf16_kernel(const float* __restrict__ src, u16* __restrict__ dst,
                                      int R, int C) {
  __shared__ float t[32][33];
  int c0 = blockIdx.x * 32, r0 = blockIdx.y * 32;
  int tx = threadIdx.x, ty = threadIdx.y;
#pragma unroll
  for (int i = 0; i < 4; i++) {
    int r = r0 + ty + i * 8;
    if (r < R && c0 + tx < C) t[ty + i * 8][tx] = src[(long)r * C + c0 + tx];
  }
  __syncthreads();
#pragma unroll
  for (int i = 0; i < 4; i++) {
    int c = c0 + ty + i * 8;
    if (c < C && r0 + tx < R) dst[(long)c * R + r0 + tx] = f2bf(t[tx][ty + i * 8]);
  }
}

// Merged tWq/tWk/tWv transpose: grid (50,50,6), z = w*2 + l.
__global__ void t_transpose3_kernel(const float* __restrict__ Wq, const float* __restrict__ Wk,
                                    const float* __restrict__ Wv, u16* __restrict__ dst0) {
  int z = blockIdx.z;
  int w = z >> 1, l = z & 1;
  const float* src = (w == 0 ? Wq : w == 1 ? Wk : Wv) + (long)l * NTD * NTD;
  u16* d = dst0 + (long)z * NTD * NTD;
  __shared__ float t[32][33];
  int c0 = blockIdx.x * 32, r0 = blockIdx.y * 32;
  int tx = threadIdx.x, ty = threadIdx.y;
#pragma unroll
  for (int i = 0; i < 4; i++) {
    int r = r0 + ty + i * 8;
    if (r < NTD && c0 + tx < NTD) t[ty + i * 8][tx] = src[(long)r * NTD + c0 + tx];
  }
  __syncthreads();
#pragma unroll
  for (int i = 0; i < 4; i++) {
    int c = c0 + ty + i * 8;
    if (c < NTD && r0 + tx < NTD) d[(long)c * NTD + r0 + tx] = f2bf(t[tx][ty + i * 8]);
  }
}

// ---------------------------------------------------------------------------
// Fused cls LayerNorm + head GEMM. grid (4,8), 256 thr (LN redone per block).
__global__ void ln_head_kernel(const float* __restrict__ x, const float* __restrict__ g,
                               const float* __restrict__ bb, const float* __restrict__ W,
                               const float* __restrict__ hb, float* __restrict__ out) {
  int b = blockIdx.y, t = threadIdx.x;
  __shared__ float xs[512];
  __shared__ float red[256];
  float v0 = x[(long)b * NM * ND + t];
  float v1 = x[(long)b * NM * ND + 256 + t];
  red[t] = v0 + v1; __syncthreads();
  for (int o = 128; o; o >>= 1) { if (t < o) red[t] += red[t + o]; __syncthreads(); }
  float mu = red[0] / 512.f; __syncthreads();
  float d0 = v0 - mu, d1 = v1 - mu;
  red[t] = d0 * d0 + d1 * d1; __syncthreads();
  for (int o = 128; o; o >>= 1) { if (t < o) red[t] += red[t + o]; __syncthreads(); }
  float inv = rsqrtf(red[0] / 512.f + 1e-5f); __syncthreads();
  xs[t] = d0 * inv * g[t] + bb[t];
  xs[256 + t] = d1 * inv * g[256 + t] + bb[256 + t];
  __syncthreads();
  int n = blockIdx.x * 250 + t;
  if (t < 250 && n < 1000) {
    float acc = hb[n];
    for (int dd = 0; dd < 512; dd++) acc += xs[dd] * W[(long)dd * 1000 + n];
    out[(long)b * 1000 + n] = acc;
  }
}

}  // namespace

extern "C" void kernel_launch(void* const* d_in, const int* in_sizes, int n_in,
                              void* d_out, int out_size, void* d_ws, size_t ws_size,
                              hipStream_t stream) {
  const float* img     = (const float*)d_in[0];
  const float* patch_W = (const float*)d_in[1];
  const float* patch_b = (const float*)d_in[2];
  const float* cls_tok = (const float*)d_in[3];
  const float* rms_s   = (const float*)d_in[4];
  const float* Wq      = (const float*)d_in[5];
  const float* Wk      = (const float*)d_in[6];
  const float* Wv      = (const float*)d_in[7];
  const float* attn_W  = (const float*)d_in[8];
  const float* attn_b  = (const float*)d_in[9];
  const float* tWq     = (const float*)d_in[10];
  const float* tWk     = (const float*)d_in[11];
  const float* tWv     = (const float*)d_in[12];
  const float* ln_g    = (const float*)d_in[13];
  const float* ln_b    = (const float*)d_in[14];
  const float* head_W  = (const float*)d_in[15];
  const float* head_b  = (const float*)d_in[16];
  float* out = (float*)d_out;

  // ---- workspace layout (floats) ----
  float* base = (float*)d_ws;
  long off = 0;
  auto alloc = [&](long n) { float* r = base + off; off += (n + 15) & ~15L; return r; };
  float* cosP = alloc(TABSZ);
  float* sinP = alloc(TABSZ);
  float* cosT = alloc(TABSZ);
  float* sinT = alloc(TABSZ);
  float* x    = alloc(XSZ);
  float* xn   = alloc(XSZ);
  float* Wt_f   = alloc(6291456);   // 48 slabs 512x512 bf16, z = l*24+w*8+h
  float* Wat_f  = alloc(2097152);   // (l) 512x4096 bf16
  float* tWt_f  = alloc(7451328);   // (w,l) 1576x1576 bf16
  float* xnb_f  = alloc(XSZ / 2);
  float* pimg_f = alloc(602112);    // 1568x768 bf16
  float* pWt_f  = alloc(196608);    // 512x768 bf16
  float* U      = alloc(16885824);  // union region
  float* ff     = alloc(64);

  u16* Wt16  = (u16*)Wt_f;
  u16* Wat16 = (u16*)Wat_f;
  u16* tWt16 = (u16*)tWt_f;
  u16* xnb   = (u16*)xnb_f;
  u16* pimg  = (u16*)pimg_f;
  u16* pWt   = (u16*)pWt_f;
  // phase A overlay (contract: kk = q + QSZ, vt = q + 2*QSZ)
  u16* q   = (u16*)U;                 // 6455296 (h, b*m, e)
  u16* kk  = q + QSZ;                 // 6455296
  u16* vt  = kk + QSZ;                // 6815744 (h,b,e,m_pad)
  float* s = (float*)(vt + 6815744);  // 2483776 f (hb,197,197)
  u16* pb  = (u16*)(s + 2483776);     // 2622464 (hb,197,208)
  u16* o   = pb + 2622464;            // 6455296 (h, b*m, e)
  float* part = (float*)q;            // 8*XSZ fp32 (aliases dead q,kk)
  // phase B overlay (contract: tkb = tqb + XSZ, tvt = tqb + 2*XSZ)
  u16* yb     = (u16*)U;              // 806912 (b*64+c, 1576)
  float* tprt = (float*)(yb + XSZ);   // 6*XSZ fp32 split partials
  u16* tqb    = (u16*)(tprt + 6 * XSZ);
  u16* tvt    = tqb + 2 * XSZ;        // (b, 1576, 64)
  float* tsp  = (float*)(tvt + XSZ);  // 8 x 8 x 64 x 64
  u16* Pb     = (u16*)(tsp + 262144); // 8*64*64

  const float rs512 = 1.f / sqrtf(512.f);
  const dim3 tt(32, 8);

  // ---- setup ----
  init_kernel<<<5114, 256, 0, stream>>>(img, cls_tok, cosP, sinP, cosT, sinT, pimg, x);
  transpose_bf16_kernel<<<dim3(16, 24), tt, 0, stream>>>(patch_W, pWt, 768, 512);
  transpose_wa_kernel<<<dim3(16, 16, 64), tt, 0, stream>>>(Wq, Wk, Wv, attn_W, Wt16, Wat16);
  t_transpose3_kernel<<<dim3(50, 50, 6), tt, 0, stream>>>(tWq, tWk, tWv, tWt16);
  mfma_gemm<EPI_PATCH><<<dim3(4, 13, 1), 256, 0, stream>>>(
      pimg, pWt, x, patch_b, 1568, 512, 768, 768, 768, 512, 1.f, 1, 0, 0, 0, 0, 0);

  for (int l = 0; l < 2; l++) {
    const float* scale = rms_s + (long)l * NM * ND;
    // ---- spatial attention ----
    rms_part_kernel<<<dim3(8, 8), 256, 0, stream>>>(x, ff);
    rms_apply_kernel<<<3152, 256, 0, stream>>>(x, scale, ff, xn, xnb);

    qkv_kernel<<<dim3(4, 13, 24), 256, 0, stream>>>(xnb, Wt16 + (long)l * 24 * 262144, q);
    rope_bf16_kernel<<<25216, 256, 0, stream>>>(q, cosP, sinP, 2L * NH * NB * NM, 512, 197);

    // scores (fp32, scaled)
    mfma_gemm<EPI_F32><<<dim3(2, 2, 64), 256, 0, stream>>>(
        q, kk, s, nullptr, 197, 197, 512, 512, 512, 197, rs512, 64,
        197L * 512, 0, 197L * 512, 0, 197L * 197);
    softmax_spatial_kernel<<<3152, 256, 0, stream>>>(s, pb);
    // o = P @ v
    mfma_gemm<EPI_BF16><<<dim3(4, 2, 64), 256, 0, stream>>>(
        pb, vt, o, nullptr, 197, 512, 197, MP, MP, 512, 1.f, 64,
        197L * MP, 0, 512L * MP, 0, 197L * 512);
    // attn-proj head partials
    mfma_gemm<EPI_F32><<<dim3(4, 13, 8), 256, 0, stream>>>(
        o, Wat16 + (long)l * 2097152, part, nullptr, 1576, 512, 512, 512, 4096, 512, 1.f, 8,
        XSZ, 0, 512, 0, XSZ);
    attn_reduce_kernel<<<3152, 256, 0, stream>>>(part, attn_b + (long)l * ND, xn, x);

    // ---- token mixing ----
    rms_part_kernel<<<dim3(8, 8), 256, 0, stream>>>(x, ff);
    rms_apply_tok_kernel<<<3152, 256, 0, stream>>>(x, scale, ff, xn, yb);

    tok_qkv_kernel<<<dim3(4, 13, 6), 256, 0, stream>>>(yb, tWt16, l, tprt);
    token_finish_kernel<<<3152, 256, 0, stream>>>(tprt, cosT, sinT, tqb);

    token_scores_kernel<<<dim3(8, 8), 256, 0, stream>>>(tqb, tqb + XSZ, tsp);
    softmax_token_kernel<<<128, 256, 0, stream>>>(tsp, Pb);
    // token PV: scatter + residual into fp32 x
    mfma_gemm<EPI_TOKPV><<<dim3(13, 1, 8), 256, 0, stream>>>(
        Pb, tvt, x, xn, 64, 1576, 64, 64, 64, 0, 1.f, 8,
        4096, 0, 1576L * 64, 0, 0);
  }

  ln_head_kernel<<<dim3(4, 8), 256, 0, stream>>>(x, ln_g, ln_b, head_W, head_b, out);
}